// Round 3
// baseline (457.928 us; speedup 1.0000x reference)
//
#include <hip/hip_runtime.h>

// Problem constants (fixed by the reference): B=8, S=512, D=384, VOCAB=50257.
#define BB 8
#define SS 512
#define DD 384
#define K2 (DD * DD)            // 147456 flattened (d,e)
#define LCH 16                  // list entries per chunk (LDS/reg resident)
#define OT 2                    // o-rows per block
#define KCH 8                   // k-chunks (grid.y); each = 48 d-rows = 18432 elems
#define CHUNK_K (K2 / KCH)      // 18432
#define NT 384                  // threads: dsub(4) x e4(96); 6 waves
#define ITERS (CHUNK_K / (4 * DD))  // 12 iters, 4 d-rows each
#define MAXL_CAP 4096

// ws layout: [0..16) count, [16..16400) list (4096 ints), [16400..) u_part
#define WS_LIST_OFF 16
#define WS_U_OFF 16400

// ---------------------------------------------------------------------------
// Kernel 1: single-wave ballot compaction of positions s2 with
// heads[b, heads[b,s2]] == 0. Deterministic order, no atomics, no memset dep.
__global__ void flag_kernel(const int* __restrict__ heads, int* __restrict__ countp,
                            int* __restrict__ list, int maxl) {
    int lane = threadIdx.x;          // 0..63
    int cnt = 0;
    for (int base = 0; base < BB * SS; base += 64) {
        int pos = base + lane;
        int b = pos >> 9;
        int h = heads[pos];
        bool c = (heads[(b << 9) + h] == 0);
        unsigned long long m = __ballot(c);
        if (c) {
            int off = cnt + (int)__popcll(m & ((1ull << lane) - 1ull));
            if (off < maxl) list[off] = pos;
        }
        cnt += (int)__popcll(m);
    }
    if (lane == 0) *countp = cnt > maxl ? maxl : cnt;
}

// ---------------------------------------------------------------------------
// Kernel 2: u_part[kc][l][o] = partial_k sum over this block's k-chunk of
// tok[l,d]*dep[l,e]*Wc[o,d,e].  Lane owns fixed e4 window (dep frags in
// REGISTERS), walks d; Wc streamed once, coalesced float4 + next-iter
// prefetch; inner-loop LDS = one <=2-addr b32 broadcast per l.
__global__ __launch_bounds__(NT) void bilinear_kernel(
    const float* __restrict__ Wc, const float* __restrict__ tok_table,
    const int* __restrict__ tokens, const int* __restrict__ list,
    const int* __restrict__ countp, float* __restrict__ u_part, int maxl) {
    __shared__ alignas(16) float tokS[LCH][DD];
    __shared__ alignas(16) float depS[LCH][DD];
    __shared__ float redS[NT / 64][LCH * OT];

    const int tid = threadIdx.x;
    const int o0 = blockIdx.x * OT;            // 192 o-pairs
    const int cb0 = blockIdx.y * CHUNK_K;      // element offset within a Wc row
    const int dbase = blockIdx.y * (CHUNK_K / DD);  // 48 d's per chunk
    const int dsub = tid / 96;                 // 0..3
    const int e4 = tid - dsub * 96;            // 0..95

    int total = *countp;
    if (total > maxl) total = maxl;

    for (int cb = 0; cb < total; cb += LCH) {
        // ---- stage tok/dep rows into LDS (zero-padded)
        for (int idx = tid; idx < LCH * DD; idx += NT) {
            int l = idx / DD;
            int i = idx - l * DD;
            float t = 0.f;
            if (cb + l < total) {
                int pos = list[cb + l];
                t = tok_table[(size_t)tokens[pos] * DD + i];
            }
            tokS[l][i] = t;
            depS[l][i] = tanhf(t);             // t==0 -> dep==0 -> contributes 0
        }
        __syncthreads();

        // ---- dep fragments into registers (fixed per lane for whole chunk)
        float4 dv[LCH];
#pragma unroll
        for (int l = 0; l < LCH; ++l) dv[l] = *(const float4*)(&depS[l][e4 * 4]);

        float acc[LCH][OT];
#pragma unroll
        for (int l = 0; l < LCH; ++l)
#pragma unroll
            for (int j = 0; j < OT; ++j) acc[l][j] = 0.f;

        // ---- stream this block's Wc chunk (2 rows), prefetched
        const float* wbase = Wc + (size_t)o0 * K2 + cb0 + tid * 4;
        float4 wv0 = *(const float4*)wbase;
        float4 wv1 = *(const float4*)(wbase + K2);

#pragma unroll 1
        for (int it = 0; it < ITERS; ++it) {
            float4 nv0 = make_float4(0.f, 0.f, 0.f, 0.f), nv1 = nv0;
            if (it + 1 < ITERS) {
                const float* wp = wbase + (it + 1) * (4 * DD);
                nv0 = *(const float4*)wp;
                nv1 = *(const float4*)(wp + K2);
            }
            int d = dbase + it * 4 + dsub;
#pragma unroll
            for (int l = 0; l < LCH; ++l) {
                float tv = tokS[l][d];
                float s0 = dv[l].x * wv0.x + dv[l].y * wv0.y + dv[l].z * wv0.z + dv[l].w * wv0.w;
                float s1 = dv[l].x * wv1.x + dv[l].y * wv1.y + dv[l].z * wv1.z + dv[l].w * wv1.w;
                acc[l][0] += tv * s0;
                acc[l][1] += tv * s1;
            }
            wv0 = nv0;
            wv1 = nv1;
        }

        // ---- block reduction: wave shuffle -> LDS -> thread-per-output store
        int wid = tid >> 6, lane = tid & 63;
#pragma unroll
        for (int l = 0; l < LCH; ++l)
#pragma unroll
            for (int j = 0; j < OT; ++j) {
                float v = acc[l][j];
                for (int off = 32; off > 0; off >>= 1) v += __shfl_down(v, off, 64);
                if (lane == 0) redS[wid][l * OT + j] = v;
            }
        __syncthreads();
        if (tid < LCH * OT) {
            float v = 0.f;
#pragma unroll
            for (int w = 0; w < NT / 64; ++w) v += redS[w][tid];
            int l = tid / OT, j = tid - l * OT;
            if (cb + l < total)
                u_part[((size_t)blockIdx.y * maxl + (cb + l)) * DD + o0 + j] = v;
        }
        __syncthreads();   // protect LDS before next chunk
    }
}

// ---------------------------------------------------------------------------
// Kernel 3: output. heads!=0 rows -> zeros (float4). heads==0 rows ->
// base[o] + sum over list entries with head==row of (tanh(u+bc)-tanh(bc))*Wr,
// where u = sum of KCH partials.
__global__ __launch_bounds__(128) void finalize_kernel(
    const int* __restrict__ heads, const float* __restrict__ Wr,
    const float* __restrict__ bc, const float* __restrict__ br,
    const int* __restrict__ list, const int* __restrict__ countp,
    const float* __restrict__ u_part, float* __restrict__ out, int maxl) {
    int row = blockIdx.x;
    int tid = threadIdx.x;
    if (heads[row] != 0) {
        if (tid < DD / 4) {
            float4 z = make_float4(0.f, 0.f, 0.f, 0.f);
            ((float4*)(out + (size_t)row * DD))[tid] = z;
        }
        return;
    }
    int b = row >> 9;
    int s1 = row & 511;

    float sumw = 0.f;
    for (int s = 0; s < SS; ++s) sumw += Wr[s];
    float brv = br[0];

    int total = *countp;
    if (total > maxl) total = maxl;

    for (int o = tid; o < DD; o += 128) {
        float bco = bc[o];
        float t_off = tanhf(bco);
        float val = t_off * sumw + brv;
        for (int l = 0; l < total; ++l) {
            int pos = list[l];
            if ((pos >> 9) == b && heads[pos] == s1) {
                float uv = 0.f;
#pragma unroll
                for (int kc = 0; kc < KCH; ++kc)
                    uv += u_part[((size_t)kc * maxl + l) * DD + o];
                val += (tanhf(uv + bco) - t_off) * Wr[pos & 511];
            }
        }
        out[(size_t)row * DD + o] = val;
    }
}

// ---------------------------------------------------------------------------
extern "C" void kernel_launch(void* const* d_in, const int* in_sizes, int n_in,
                              void* d_out, int out_size, void* d_ws, size_t ws_size,
                              hipStream_t stream) {
    const int* tokens = (const int*)d_in[0];
    // d_in[1] = dep_types: computed-but-discarded in the reference (bug preserved)
    const int* heads = (const int*)d_in[2];
    const float* tok_table = (const float*)d_in[3];
    const float* Wc = (const float*)d_in[4];
    const float* bc = (const float*)d_in[5];
    const float* Wr = (const float*)d_in[6];
    const float* br = (const float*)d_in[7];
    float* out = (float*)d_out;

    char* ws = (char*)d_ws;
    int* countp = (int*)ws;
    int* list = (int*)(ws + WS_LIST_OFF);
    float* u_part = (float*)(ws + WS_U_OFF);

    long maxl_l = ((long)ws_size - WS_U_OFF) / ((long)KCH * DD * 4);
    int maxl = maxl_l < 0 ? 0 : (maxl_l > MAXL_CAP ? MAXL_CAP : (int)maxl_l);

    // No memset needed: count/list written by flag before readers (stream
    // order); u_part slices are exclusively owned and fully written per use.
    flag_kernel<<<1, 64, 0, stream>>>(heads, countp, list, maxl);
    bilinear_kernel<<<dim3(DD / OT, KCH), NT, 0, stream>>>(
        Wc, tok_table, tokens, list, countp, u_part, maxl);
    finalize_kernel<<<BB * SS, 128, 0, stream>>>(
        heads, Wr, bc, br, list, countp, u_part, out, maxl);
}